// Round 1
// 328.349 us; speedup vs baseline: 1.1319x; 1.1319x over previous
//
#include <hip/hip_runtime.h>
#include <cstdint>

#define NB 8
#define NN 2048
#define DD 1024
#define DD2 2048
#define BK 64

typedef short short8 __attribute__((ext_vector_type(8)));
typedef float floatx4 __attribute__((ext_vector_type(4)));

// fp32 -> bf16 round-to-nearest-even (no NaN special-casing; inputs are finite)
__device__ __forceinline__ unsigned short f2bf(float f) {
    unsigned int u = __float_as_uint(f);
    u += 0x7fffu + ((u >> 16) & 1u);
    return (unsigned short)(u >> 16);
}

// async global->LDS, 16B per lane. LDS dest is wave-uniform base + lane*16.
__device__ __forceinline__ void async_copy16(const void* g, void* l) {
    __builtin_amdgcn_global_load_lds(
        (__attribute__((address_space(1))) void*)(uintptr_t)g,
        (__attribute__((address_space(3))) void*)(unsigned int)(uintptr_t)l,
        16, 0, 0);
}

// ---------------------------------------------------------------------------
// Kernel 1: per-row L2 norm of x0 = x[:, :, :1024]; write xn (bf16).
// One wave per row; fully coalesced float4 loads, 8B bf16 stores.
// ---------------------------------------------------------------------------
__global__ __launch_bounds__(256) void k_norm(const float* __restrict__ x,
                                              unsigned short* __restrict__ xn) {
    int row  = blockIdx.x * 4 + (threadIdx.x >> 6);
    int lane = threadIdx.x & 63;
    const float* xr = x + (size_t)row * DD2;   // x0 = first 1024 floats of row
    float4 v[4];
    float s = 0.f;
#pragma unroll
    for (int i = 0; i < 4; i++) {
        v[i] = ((const float4*)xr)[lane + i * 64];
        s += v[i].x * v[i].x + v[i].y * v[i].y + v[i].z * v[i].z + v[i].w * v[i].w;
    }
#pragma unroll
    for (int off = 32; off >= 1; off >>= 1) s += __shfl_xor(s, off, 64);
    float inv = 1.0f / sqrtf(s + 1e-8f);
    unsigned short* xnr = xn + (size_t)row * DD;
#pragma unroll
    for (int i = 0; i < 4; i++) {
        ushort4 o;
        o.x = f2bf(v[i].x * inv);
        o.y = f2bf(v[i].y * inv);
        o.z = f2bf(v[i].z * inv);
        o.w = f2bf(v[i].w * inv);
        ((ushort4*)xnr)[lane + i * 64] = o;
    }
}

// ---------------------------------------------------------------------------
// Kernel 2: cast+transpose x0 -> x0t[b][d][n] (bf16), 64x64 LDS tiles.
// Needed so the second GEMM's B-operand is row-major over K (= m).
// ---------------------------------------------------------------------------
__global__ __launch_bounds__(256) void k_transpose(const float* __restrict__ x,
                                                   unsigned short* __restrict__ x0t) {
    __shared__ unsigned short tile[64 * 68];   // stride 68 shorts: 8B-aligned rows, no pow2
    int b  = blockIdx.y;
    int t  = blockIdx.x;       // 0..511
    int nt = t >> 4;           // 0..31
    int dt = t & 15;           // 0..15
    int n0 = nt * 64, d0 = dt * 64;
    int tid = threadIdx.x;
    int r  = tid >> 4;         // 0..15
    int c4 = tid & 15;         // 0..15
    const float* xb = x + (size_t)b * NN * DD2;
#pragma unroll
    for (int p = 0; p < 4; p++) {
        int n = p * 16 + r;
        float4 v = *(const float4*)&xb[(size_t)(n0 + n) * DD2 + d0 + c4 * 4];
        tile[(c4 * 4 + 0) * 68 + n] = f2bf(v.x);
        tile[(c4 * 4 + 1) * 68 + n] = f2bf(v.y);
        tile[(c4 * 4 + 2) * 68 + n] = f2bf(v.z);
        tile[(c4 * 4 + 3) * 68 + n] = f2bf(v.w);
    }
    __syncthreads();
    unsigned short* ob = x0t + (size_t)b * DD * NN;
#pragma unroll
    for (int p = 0; p < 4; p++) {
        int d = p * 16 + r;
        ushort4 o;
        o.x = tile[d * 68 + c4 * 4 + 0];
        o.y = tile[d * 68 + c4 * 4 + 1];
        o.z = tile[d * 68 + c4 * 4 + 2];
        o.w = tile[d * 68 + c4 * 4 + 3];
        *(ushort4*)&ob[(size_t)(d0 + d) * NN + n0 + c4 * 4] = o;
    }
}

// ---------------------------------------------------------------------------
// Shared GEMM core: C[128x128] += A[128xK] * B[128xK]^T (gemm_bt), bf16 MFMA.
// 4 waves in 2x2, each owns 4x4 tiles of 16x16. BK=64 per iteration.
// 2-PHASE double-buffered pipeline: stage(t+1) is issued BEFORE compute(t);
// counted s_waitcnt vmcnt(8) keeps next tile's 8 loads in flight across the
// barrier (raw s_barrier, NOT __syncthreads -- no vmcnt(0) drain).
// Staging: global_load_lds 16B/lane, XOR slot swizzle (slot ^= row&7) so the
// frag ds_read_b128s land on distinct bank groups (<=2-way = free, m136).
// ---------------------------------------------------------------------------
__device__ __forceinline__ void stage_tile(const unsigned short* gbase, int ld,
                                           unsigned short* lds, int w, int lane) {
    int rgrp = lane >> 3;              // 0..7 row within 8-row group
    int slot = lane & 7;               // 0..7 16B slot within 128B row
    int sw   = slot ^ rgrp;            // r&7 == rgrp (group bases are mult of 8)
#pragma unroll
    for (int j = 0; j < 4; j++) {
        int r = j * 32 + w * 8 + rgrp;
        const unsigned short* g = gbase + (size_t)r * ld + sw * 8;
        unsigned short* l = lds + (j * 32 + w * 8) * BK;  // wave-uniform base
        async_copy16((void*)g, (void*)l);
    }
}

__device__ __forceinline__ short8 read_frag(const unsigned short* lds, int row, int g) {
    int slot = g ^ (row & 7);
    return *(const short8*)(lds + row * BK + slot * 8);
}

__device__ __forceinline__ void gemm_core(const unsigned short* __restrict__ Ag, int lda,
                                          const unsigned short* __restrict__ Bg, int ldb,
                                          int kIters,
                                          unsigned short* As0, unsigned short* Bs0,
                                          unsigned short* As1, unsigned short* Bs1,
                                          floatx4 acc[4][4]) {
    int tid  = threadIdx.x;
    int w    = tid >> 6, lane = tid & 63;
    int wr   = (w >> 1) * 64, wc = (w & 1) * 64;
    int lrow = lane & 15, quad = lane >> 4;

    // prologue: stage tile 0 into buffer 0 (8 loads/wave in flight)
    stage_tile(Ag, lda, As0, w, lane);
    stage_tile(Bg, ldb, Bs0, w, lane);

    for (int kt = 0; kt < kIters; kt++) {
        unsigned short* Ac = (kt & 1) ? As1 : As0;
        unsigned short* Bc = (kt & 1) ? Bs1 : Bs0;
        if (kt + 1 < kIters) {
            // issue next tile's 8 loads into the alternate buffer, then wait
            // only for the CURRENT tile (oldest 8): vmcnt(8), not 0.
            unsigned short* An = (kt & 1) ? As0 : As1;
            unsigned short* Bn = (kt & 1) ? Bs0 : Bs1;
            stage_tile(Ag + (size_t)(kt + 1) * BK, lda, An, w, lane);
            stage_tile(Bg + (size_t)(kt + 1) * BK, ldb, Bn, w, lane);
            asm volatile("s_waitcnt vmcnt(8)" ::: "memory");
        } else {
            asm volatile("s_waitcnt vmcnt(0)" ::: "memory");
        }
        __builtin_amdgcn_s_barrier();          // current tile visible to all waves
        asm volatile("" ::: "memory");         // no LDS reads hoisted above barrier
#pragma unroll
        for (int s = 0; s < 2; s++) {
            short8 af[4], bf[4];
#pragma unroll
            for (int t = 0; t < 4; t++) af[t] = read_frag(Ac, wr + t * 16 + lrow, s * 4 + quad);
#pragma unroll
            for (int t = 0; t < 4; t++) bf[t] = read_frag(Bc, wc + t * 16 + lrow, s * 4 + quad);
#pragma unroll
            for (int ti = 0; ti < 4; ti++)
#pragma unroll
                for (int tj = 0; tj < 4; tj++)
                    acc[ti][tj] = __builtin_amdgcn_mfma_f32_16x16x32_bf16(
                        af[ti], bf[tj], acc[ti][tj], 0, 0, 0);
        }
        asm volatile("" ::: "memory");
        __builtin_amdgcn_s_barrier();          // all reads of this buffer done
                                               // before iter kt+1 overwrites it
    }
}

// ---------------------------------------------------------------------------
// Kernel 3: attn[b][n][m] = tril(sp)[n][m] * (xn[b][n] . xn[b][m]), bf16 out.
// Only causal tile pairs (mt <= nt): 136 blocks per batch.
// Flat grid + XCD pinning: b = L&7 so batch b runs on XCD b -> xn[b] (4 MB)
// is L2-resident for the whole kernel.
// ---------------------------------------------------------------------------
__global__ __launch_bounds__(256) void k_cosim(const unsigned short* __restrict__ xn,
                                               const float* __restrict__ sp,
                                               unsigned short* __restrict__ attn) {
    __shared__ __attribute__((aligned(16))) unsigned short As0[128 * BK];
    __shared__ __attribute__((aligned(16))) unsigned short Bs0[128 * BK];
    __shared__ __attribute__((aligned(16))) unsigned short As1[128 * BK];
    __shared__ __attribute__((aligned(16))) unsigned short Bs1[128 * BK];
    int L = blockIdx.x;                 // 0..1087
    int b = L & 7;                      // batch == XCD (dispatch round-robins %8)
    int p = L >> 3;                     // 0..135 -> (nt, mt) with mt<=nt
    int nt = 0;
    while ((nt + 1) * (nt + 2) / 2 <= p) nt++;
    int mt = p - nt * (nt + 1) / 2;
    int n0 = nt * 128, m0 = mt * 128;
    const unsigned short* xb = xn + (size_t)b * NN * DD;

    floatx4 acc[4][4];
#pragma unroll
    for (int i = 0; i < 4; i++)
#pragma unroll
        for (int j = 0; j < 4; j++) acc[i][j] = (floatx4)0.0f;

    gemm_core(xb + (size_t)n0 * DD, DD, xb + (size_t)m0 * DD, DD, DD / BK,
              As0, Bs0, As1, Bs1, acc);

    int tid = threadIdx.x, w = tid >> 6, lane = tid & 63;
    int wr = (w >> 1) * 64, wc = (w & 1) * 64;
    int col = lane & 15, quad = lane >> 4;
    unsigned short* ab = attn + (size_t)b * NN * NN;
#pragma unroll
    for (int ti = 0; ti < 4; ti++)
#pragma unroll
        for (int tj = 0; tj < 4; tj++)
#pragma unroll
            for (int r = 0; r < 4; r++) {
                int n = n0 + wr + ti * 16 + quad * 4 + r;
                int m = m0 + wc + tj * 16 + col;
                float v = acc[ti][tj][r];
                float s = sp[(size_t)n * NN + m];
                float o = (m <= n) ? s * v : 0.0f;   // tril mask (diagonal tiles)
                ab[(size_t)n * NN + m] = f2bf(o);
            }
}

// ---------------------------------------------------------------------------
// Kernel 4: out[b][n][d] = (attn[b][n][:K] . x0t[b][d][:K]) * x1[b][n][d]
// K = (nt+1)*128 (causal). Flat grid + XCD pinning: b = L&7, so x0t[b]
// (exactly 4 MB = one XCD's L2) is resident, and the 8 dt-sibling blocks
// sharing one attn panel are concurrent on the SAME XCD. nt descending
// within each XCD so long-K blocks launch first.
// ---------------------------------------------------------------------------
__global__ __launch_bounds__(256) void k_ctx(const unsigned short* __restrict__ attn,
                                             const unsigned short* __restrict__ x0t,
                                             const float* __restrict__ x,
                                             float* __restrict__ out) {
    __shared__ __attribute__((aligned(16))) unsigned short As0[128 * BK];
    __shared__ __attribute__((aligned(16))) unsigned short Bs0[128 * BK];
    __shared__ __attribute__((aligned(16))) unsigned short As1[128 * BK];
    __shared__ __attribute__((aligned(16))) unsigned short Bs1[128 * BK];
    int L = blockIdx.x;                 // 0..1023
    int b = L & 7;                      // batch == XCD
    int j = L >> 3;                     // 0..127
    int nt = 15 - (j >> 3);             // descending cost within XCD
    int dt = j & 7;
    int n0 = nt * 128, d0 = dt * 128;
    const unsigned short* Ab = attn + (size_t)b * NN * NN + (size_t)n0 * NN;
    const unsigned short* Bb = x0t + (size_t)b * DD * NN + (size_t)d0 * NN;

    floatx4 acc[4][4];
#pragma unroll
    for (int i = 0; i < 4; i++)
#pragma unroll
        for (int jj = 0; jj < 4; jj++) acc[i][jj] = (floatx4)0.0f;

    gemm_core(Ab, NN, Bb, NN, (nt + 1) * 2, As0, Bs0, As1, Bs1, acc);

    int tid = threadIdx.x, w = tid >> 6, lane = tid & 63;
    int wr = (w >> 1) * 64, wc = (w & 1) * 64;
    int col = lane & 15, quad = lane >> 4;
#pragma unroll
    for (int ti = 0; ti < 4; ti++)
#pragma unroll
        for (int tj = 0; tj < 4; tj++)
#pragma unroll
            for (int r = 0; r < 4; r++) {
                int n = n0 + wr + ti * 16 + quad * 4 + r;
                int d = d0 + wc + tj * 16 + col;
                float x1 = x[((size_t)b * NN + n) * DD2 + DD + d];
                out[((size_t)b * NN + n) * DD + d] = acc[ti][tj][r] * x1;
            }
}

extern "C" void kernel_launch(void* const* d_in, const int* in_sizes, int n_in,
                              void* d_out, int out_size, void* d_ws, size_t ws_size,
                              hipStream_t stream) {
    const float* x  = (const float*)d_in[0];
    const float* sp = (const float*)d_in[1];
    float* out = (float*)d_out;

    unsigned short* xn   = (unsigned short*)d_ws;                      // 33.5 MB
    unsigned short* x0t  = xn + (size_t)NB * NN * DD;                  // 33.5 MB
    unsigned short* attn = x0t + (size_t)NB * NN * DD;                 // 67 MB

    hipLaunchKernelGGL(k_norm,      dim3(NB * NN / 4), dim3(256), 0, stream, x, xn);
    hipLaunchKernelGGL(k_transpose, dim3(512, NB),     dim3(256), 0, stream, x, x0t);
    hipLaunchKernelGGL(k_cosim,     dim3(136 * NB),    dim3(256), 0, stream, xn, sp, attn);
    hipLaunchKernelGGL(k_ctx,       dim3(128 * NB),    dim3(256), 0, stream, attn, x0t, x, out);
}